// Round 1
// baseline (292.272 us; speedup 1.0000x reference)
//
#include <hip/hip_runtime.h>

#define DEVINL __device__ __forceinline__

typedef __attribute__((ext_vector_type(8))) __bf16          bf16x8;
typedef __attribute__((ext_vector_type(4))) float           f32x4;
typedef __attribute__((ext_vector_type(8))) unsigned short  ushort8;
typedef __attribute__((ext_vector_type(4))) unsigned short  ushort4v;
typedef __attribute__((ext_vector_type(4))) float           float4v;

DEVINL unsigned short f2bf(float f) {
  unsigned int u = __float_as_uint(f);
  u += 0x7fffu + ((u >> 16) & 1u);   // round-to-nearest-even
  return (unsigned short)(u >> 16);
}

DEVINL bf16x8 ldbf8(const unsigned short* p) {
  return __builtin_bit_cast(bf16x8, *(const ushort8*)p);
}

// ---------------- fp32 -> bf16 elementwise ----------------
__global__ __launch_bounds__(256) void cvt_f32_bf16_kernel(
    const float* __restrict__ in, unsigned short* __restrict__ out, int n4) {
  int i = blockIdx.x * 256 + threadIdx.x;
  const int stride = gridDim.x * 256;
  for (; i < n4; i += stride) {
    float4v v = *(const float4v*)(in + (size_t)4 * i);
    ushort4v o;
    o[0] = f2bf(v[0]); o[1] = f2bf(v[1]); o[2] = f2bf(v[2]); o[3] = f2bf(v[3]);
    *(ushort4v*)(out + (size_t)4 * i) = o;
  }
}

// ---------------- fp32 (RxC) -> bf16 transposed (CxR) ----------------
__global__ __launch_bounds__(256) void transpose_cvt_kernel(
    const float* __restrict__ in, unsigned short* __restrict__ out, int R, int C) {
  __shared__ float tile[32][33];
  const int tx = threadIdx.x & 31, ty = threadIdx.x >> 5;
  const int r0 = blockIdx.y << 5, c0 = blockIdx.x << 5;
#pragma unroll
  for (int i = 0; i < 32; i += 8)
    tile[ty + i][tx] = in[(size_t)(r0 + ty + i) * C + (c0 + tx)];
  __syncthreads();
#pragma unroll
  for (int i = 0; i < 32; i += 8)
    out[(size_t)(c0 + ty + i) * R + (r0 + tx)] = f2bf(tile[tx][ty + i]);
}

// ---------------- bf16 GEMM: C = A(MxK) * Bt(NxK)^T ----------------
// 128x128 tile, BK=32, 4 waves (2x2), each wave 64x64 via 4x4 x (16x16x32) MFMA.
template <bool OUT_BF16>
__global__ __launch_bounds__(256) void gemm_bt_kernel(
    const unsigned short* __restrict__ A,   // M x K, lda
    const unsigned short* __restrict__ Bt,  // N x K, ldb
    void* __restrict__ Cout,                // M x N, ldc
    int M, int N, int K, int lda, int ldb, int ldc) {
  __shared__ __align__(16) unsigned short As[128 * 32];
  __shared__ __align__(16) unsigned short Bs[128 * 32];
  const int tid = threadIdx.x;
  const int lane = tid & 63, wave = tid >> 6;
  const int wr = wave >> 1, wc = wave & 1;
  const int g = lane >> 4, q = lane & 15;
  const int row0 = blockIdx.x << 7, col0 = blockIdx.y << 7;

  // staging: thread t covers 8 contiguous k at row tid>>2 (+64 for 2nd issue)
  const int srow = tid >> 2, skcol = (tid & 3) << 3;
  const unsigned short* Ap0 = A + (size_t)(row0 + srow) * lda + skcol;
  const unsigned short* Ap1 = Ap0 + (size_t)64 * lda;
  const unsigned short* Bp0 = Bt + (size_t)(col0 + srow) * ldb + skcol;
  const unsigned short* Bp1 = Bp0 + (size_t)64 * ldb;

  f32x4 acc[4][4] = {};

  ushort8 ra0 = *(const ushort8*)Ap0, ra1 = *(const ushort8*)Ap1;
  ushort8 rb0 = *(const ushort8*)Bp0, rb1 = *(const ushort8*)Bp1;

  for (int k0 = 32;; k0 += 32) {
    *(ushort8*)(As + tid * 8)        = ra0;
    *(ushort8*)(As + 2048 + tid * 8) = ra1;
    *(ushort8*)(Bs + tid * 8)        = rb0;
    *(ushort8*)(Bs + 2048 + tid * 8) = rb1;
    __syncthreads();
    const bool more = (k0 < K);
    if (more) {  // prefetch next K-tile into regs; latency hides under MFMAs
      Ap0 += 32; Ap1 += 32; Bp0 += 32; Bp1 += 32;
      ra0 = *(const ushort8*)Ap0; ra1 = *(const ushort8*)Ap1;
      rb0 = *(const ushort8*)Bp0; rb1 = *(const ushort8*)Bp1;
    }
    bf16x8 af[4], bfr[4];
#pragma unroll
    for (int mb = 0; mb < 4; ++mb)
      af[mb] = ldbf8(As + (wr * 64 + mb * 16 + q) * 32 + g * 8);
#pragma unroll
    for (int nb = 0; nb < 4; ++nb)
      bfr[nb] = ldbf8(Bs + (wc * 64 + nb * 16 + q) * 32 + g * 8);
#pragma unroll
    for (int mb = 0; mb < 4; ++mb)
#pragma unroll
      for (int nb = 0; nb < 4; ++nb)
        acc[mb][nb] = __builtin_amdgcn_mfma_f32_16x16x32_bf16(af[mb], bfr[nb], acc[mb][nb], 0, 0, 0);
    if (!more) break;
    __syncthreads();
  }

#pragma unroll
  for (int mb = 0; mb < 4; ++mb)
#pragma unroll
    for (int nb = 0; nb < 4; ++nb)
#pragma unroll
      for (int r = 0; r < 4; ++r) {
        const int row = row0 + wr * 64 + mb * 16 + g * 4 + r;  // C/D: row=(l>>4)*4+reg
        const int col = col0 + wc * 64 + nb * 16 + q;          //       col=l&15
        const float v = acc[mb][nb][r];
        if (OUT_BF16) ((unsigned short*)Cout)[(size_t)row * ldc + col] = f2bf(v);
        else          ((float*)Cout)[(size_t)row * ldc + col] = v;
      }
}

// ---------------- causal flash attention ----------------
// 1 wave per 32 Q-rows; KV tiles of 32; online softmax in fp32.
__global__ __launch_bounds__(64) void attn_kernel(
    const unsigned short* __restrict__ qkv,  // (B*S) x 3H row-major
    unsigned short* __restrict__ O) {        // (B*S) x H row-major
  const int S = 2048, H = 1024, LD = 3072, DH = 64;
  const int qt = blockIdx.x, h = blockIdx.y, b = blockIdx.z;
  const int lane = threadIdx.x;
  const int g = lane >> 4, q = lane & 15;
  const int q0 = qt << 5;

  const unsigned short* Qb = qkv + (size_t)b * S * LD + h * DH;
  const unsigned short* Kb = Qb + H;
  const unsigned short* Vb = Qb + 2 * H;

  // Q fragments held in registers for the whole row-tile
  bf16x8 qf[2][2];
#pragma unroll
  for (int mb = 0; mb < 2; ++mb)
#pragma unroll
    for (int kc = 0; kc < 2; ++kc)
      qf[mb][kc] = ldbf8(Qb + (size_t)(q0 + mb * 16 + q) * LD + kc * 32 + g * 8);

  __shared__ __align__(16) unsigned short Vt[64 * 32];  // Vt[d][c] = V[c][d]
  __shared__ __align__(16) unsigned short Pl[32 * 32];

  f32x4 acc_o[2][4] = {};
  float m_r[2][4], l_r[2][4];
#pragma unroll
  for (int mb = 0; mb < 2; ++mb)
#pragma unroll
    for (int r = 0; r < 4; ++r) { m_r[mb][r] = -1e30f; l_r[mb][r] = 0.f; }

  const int vc = lane >> 1, vd0 = (lane & 1) << 5;

  for (int t = 0; t <= qt; ++t) {
    const int c0 = t << 5;
    // K fragments straight from global (K/V L2-resident per head)
    bf16x8 kf[2][2];
#pragma unroll
    for (int nb = 0; nb < 2; ++nb)
#pragma unroll
      for (int kc = 0; kc < 2; ++kc)
        kf[nb][kc] = ldbf8(Kb + (size_t)(c0 + nb * 16 + q) * LD + kc * 32 + g * 8);
    // stage V tile transposed into LDS (coalesced global read, scalar LDS scatter)
    {
      const unsigned short* vp = Vb + (size_t)(c0 + vc) * LD + vd0;
      ushort8 vv[4];
#pragma unroll
      for (int j = 0; j < 4; ++j) vv[j] = *(const ushort8*)(vp + j * 8);
#pragma unroll
      for (int j = 0; j < 4; ++j)
#pragma unroll
        for (int e = 0; e < 8; ++e)
          Vt[(vd0 + j * 8 + e) * 32 + vc] = vv[j][e];
    }
    // S = Q K^T / sqrt(dh)
    f32x4 s[2][2] = {};
#pragma unroll
    for (int kc = 0; kc < 2; ++kc)
#pragma unroll
      for (int mb = 0; mb < 2; ++mb)
#pragma unroll
        for (int nb = 0; nb < 2; ++nb)
          s[mb][nb] = __builtin_amdgcn_mfma_f32_16x16x32_bf16(qf[mb][kc], kf[nb][kc], s[mb][nb], 0, 0, 0);
#pragma unroll
    for (int mb = 0; mb < 2; ++mb)
#pragma unroll
      for (int nb = 0; nb < 2; ++nb)
        s[mb][nb] *= 0.125f;
    if (t == qt) {  // only the diagonal tile needs masking
#pragma unroll
      for (int mb = 0; mb < 2; ++mb)
#pragma unroll
        for (int nb = 0; nb < 2; ++nb)
#pragma unroll
          for (int r = 0; r < 4; ++r) {
            const int rr = q0 + mb * 16 + g * 4 + r;
            const int cc = c0 + nb * 16 + q;
            if (cc > rr) s[mb][nb][r] = -1e30f;
          }
    }
    // online softmax; row stats via 16-lane butterfly (rows live in lanes sharing g)
    float sf_[2][4];
#pragma unroll
    for (int mb = 0; mb < 2; ++mb)
#pragma unroll
      for (int r = 0; r < 4; ++r) {
        float mx = fmaxf(s[mb][0][r], s[mb][1][r]);
#pragma unroll
        for (int off = 1; off < 16; off <<= 1) mx = fmaxf(mx, __shfl_xor(mx, off));
        const float mn = fmaxf(m_r[mb][r], mx);
        const float sf = __expf(m_r[mb][r] - mn);
        m_r[mb][r] = mn;
        const float p0 = __expf(s[mb][0][r] - mn);
        const float p1 = __expf(s[mb][1][r] - mn);
        Pl[(mb * 16 + g * 4 + r) * 32 + q]      = f2bf(p0);
        Pl[(mb * 16 + g * 4 + r) * 32 + 16 + q] = f2bf(p1);
        float rs = p0 + p1;
#pragma unroll
        for (int off = 1; off < 16; off <<= 1) rs += __shfl_xor(rs, off);
        l_r[mb][r] = l_r[mb][r] * sf + rs;
        sf_[mb][r] = sf;
      }
#pragma unroll
    for (int mb = 0; mb < 2; ++mb)
#pragma unroll
      for (int db = 0; db < 4; ++db)
#pragma unroll
        for (int r = 0; r < 4; ++r)
          acc_o[mb][db][r] *= sf_[mb][r];
    __syncthreads();  // P/Vt writes -> visible for fragment reads
    // O += P V
    bf16x8 pa[2], vf[4];
#pragma unroll
    for (int mb = 0; mb < 2; ++mb) pa[mb] = ldbf8(Pl + (mb * 16 + q) * 32 + g * 8);
#pragma unroll
    for (int db = 0; db < 4; ++db) vf[db] = ldbf8(Vt + (db * 16 + q) * 32 + g * 8);
#pragma unroll
    for (int mb = 0; mb < 2; ++mb)
#pragma unroll
      for (int db = 0; db < 4; ++db)
        acc_o[mb][db] = __builtin_amdgcn_mfma_f32_16x16x32_bf16(pa[mb], vf[db], acc_o[mb][db], 0, 0, 0);
    __syncthreads();  // protect Vt/Pl before next iteration overwrites
  }
#pragma unroll
  for (int mb = 0; mb < 2; ++mb)
#pragma unroll
    for (int db = 0; db < 4; ++db)
#pragma unroll
      for (int r = 0; r < 4; ++r) {
        const int row = q0 + mb * 16 + g * 4 + r;
        const int col = h * DH + db * 16 + q;
        O[(size_t)(b * S + row) * H + col] = f2bf(acc_o[mb][db][r] / l_r[mb][r]);
      }
}

extern "C" void kernel_launch(void* const* d_in, const int* in_sizes, int n_in,
                              void* d_out, int out_size, void* d_ws, size_t ws_size,
                              hipStream_t stream) {
  const float* x     = (const float*)d_in[0];
  const float* w_qkv = (const float*)d_in[1];
  const float* w_out = (const float*)d_in[2];
  const int B = 2, S = 2048, H = 1024;
  const int M = B * S;  // 4096

  // workspace layout (ushort elements), total 48 MB:
  unsigned short* xb    = (unsigned short*)d_ws;        // M*H      (8 MB)
  unsigned short* wqkvT = xb + (size_t)M * H;           // 3H*H     (6 MB)
  unsigned short* woutT = wqkvT + (size_t)3 * H * H;    // H*H      (2 MB)
  unsigned short* qkvb  = woutT + (size_t)H * H;        // M*3H    (24 MB)
  unsigned short* Ob    = qkvb + (size_t)M * 3 * H;     // M*H      (8 MB)

  cvt_f32_bf16_kernel<<<1024, 256, 0, stream>>>(x, xb, (M * H) / 4);
  transpose_cvt_kernel<<<dim3((3 * H) / 32, H / 32), 256, 0, stream>>>(w_qkv, wqkvT, H, 3 * H);
  transpose_cvt_kernel<<<dim3(H / 32, H / 32), 256, 0, stream>>>(w_out, woutT, H, H);

  // qkv = x @ w_qkv  (bf16 out, feeds attention)
  gemm_bt_kernel<true><<<dim3(M / 128, (3 * H) / 128), 256, 0, stream>>>(
      xb, wqkvT, qkvb, M, 3 * H, H, H, H, 3 * H);

  // causal multi-head attention
  attn_kernel<<<dim3(S / 32, 16, B), 64, 0, stream>>>(qkvb, Ob);

  // out = attn @ w_out (fp32 out)
  gemm_bt_kernel<false><<<dim3(M / 128, H / 128), 256, 0, stream>>>(
      Ob, woutT, d_out, M, H, H, H, H, H);
}

// Round 2
// 199.230 us; speedup vs baseline: 1.4670x; 1.4670x over previous
//
#include <hip/hip_runtime.h>

#define DEVINL __device__ __forceinline__

typedef __attribute__((ext_vector_type(8))) __bf16          bf16x8;
typedef __attribute__((ext_vector_type(4))) float           f32x4;
typedef __attribute__((ext_vector_type(8))) unsigned short  ushort8;
typedef __attribute__((ext_vector_type(4))) unsigned short  ushort4v;
typedef __attribute__((ext_vector_type(4))) float           float4v;

DEVINL unsigned short f2bf(float f) {
  unsigned int u = __float_as_uint(f);
  u += 0x7fffu + ((u >> 16) & 1u);   // round-to-nearest-even
  return (unsigned short)(u >> 16);
}

DEVINL bf16x8 ldbf8(const unsigned short* p) {
  return __builtin_bit_cast(bf16x8, *(const ushort8*)p);
}

// async global->LDS, 16B per lane; LDS dest = wave-uniform base + lane*16
DEVINL void gload_lds16(const unsigned short* g, unsigned short* l) {
  __builtin_amdgcn_global_load_lds((const __attribute__((address_space(1))) void*)g,
                                   (__attribute__((address_space(3))) void*)l, 16, 0, 0);
}

// ---------------- fp32 -> bf16 elementwise ----------------
__global__ __launch_bounds__(256) void cvt_f32_bf16_kernel(
    const float* __restrict__ in, unsigned short* __restrict__ out, int n4) {
  int i = blockIdx.x * 256 + threadIdx.x;
  const int stride = gridDim.x * 256;
  for (; i < n4; i += stride) {
    float4v v = *(const float4v*)(in + (size_t)4 * i);
    ushort4v o;
    o[0] = f2bf(v[0]); o[1] = f2bf(v[1]); o[2] = f2bf(v[2]); o[3] = f2bf(v[3]);
    *(ushort4v*)(out + (size_t)4 * i) = o;
  }
}

// ---------------- fp32 (RxC) -> bf16 transposed (CxR) ----------------
__global__ __launch_bounds__(256) void transpose_cvt_kernel(
    const float* __restrict__ in, unsigned short* __restrict__ out, int R, int C) {
  __shared__ float tile[32][33];
  const int tx = threadIdx.x & 31, ty = threadIdx.x >> 5;
  const int r0 = blockIdx.y << 5, c0 = blockIdx.x << 5;
#pragma unroll
  for (int i = 0; i < 32; i += 8)
    tile[ty + i][tx] = in[(size_t)(r0 + ty + i) * C + (c0 + tx)];
  __syncthreads();
#pragma unroll
  for (int i = 0; i < 32; i += 8)
    out[(size_t)(c0 + ty + i) * R + (r0 + tx)] = f2bf(tile[tx][ty + i]);
}

// ---------------- bf16 V transpose: qkv V-third -> Vt[(b,h,d)][s] ----------------
__global__ __launch_bounds__(256) void v_transpose_kernel(
    const unsigned short* __restrict__ qkv, unsigned short* __restrict__ VtG) {
  const int S = 2048, LD = 3072;
  const int s0 = blockIdx.x << 5;
  const int bh = blockIdx.y;           // b*16 + h
  const int b = bh >> 4, h = bh & 15;
  __shared__ __align__(16) unsigned short T[32][72];  // 16B-aligned rows
  const int t = threadIdx.x;
  {
    const int s = t >> 3, d0 = (t & 7) << 3;
    *(ushort8*)&T[s][d0] =
        *(const ushort8*)(qkv + ((size_t)(b * S) + s0 + s) * LD + 2048 + h * 64 + d0);
  }
  __syncthreads();
  {
    const int d = t >> 2, sc = (t & 3) << 3;
    ushort8 o;
#pragma unroll
    for (int e = 0; e < 8; ++e) o[e] = T[sc + e][d];
    *(ushort8*)(VtG + ((size_t)bh * 64 + d) * S + s0 + sc) = o;
  }
}

// ---------------- bf16 GEMM: C = A(MxK) * Bt(NxK)^T ----------------
// 128x128 tile, BK=32, 4 waves (2x2), global_load_lds staging (m97 structure).
template <bool OUT_BF16>
__global__ __launch_bounds__(256) void gemm_bt_kernel(
    const unsigned short* __restrict__ A,   // M x K, lda
    const unsigned short* __restrict__ Bt,  // N x K, ldb
    void* __restrict__ Cout,                // M x N, ldc
    int M, int N, int K, int lda, int ldb, int ldc) {
  __shared__ __align__(16) unsigned short As[128 * 32];
  __shared__ __align__(16) unsigned short Bs[128 * 32];
  const int tid = threadIdx.x;
  const int lane = tid & 63, wave = tid >> 6;
  const int wr = wave >> 1, wc = wave & 1;
  const int g = lane >> 4, q = lane & 15;
  const int row0 = blockIdx.x << 7, col0 = blockIdx.y << 7;

  // staging: thread t covers 8 contiguous k at row t>>2 (+64 for 2nd issue)
  const int srow = tid >> 2, skcol = (tid & 3) << 3;
  const unsigned short* Ap0 = A + (size_t)(row0 + srow) * lda + skcol;
  const unsigned short* Ap1 = Ap0 + (size_t)64 * lda;
  const unsigned short* Bp0 = Bt + (size_t)(col0 + srow) * ldb + skcol;
  const unsigned short* Bp1 = Bp0 + (size_t)64 * ldb;
  unsigned short* Asw = As + wave * 512;  // wave-uniform LDS base (w*1024 B)
  unsigned short* Bsw = Bs + wave * 512;

  f32x4 acc[4][4] = {};

  for (int k0 = 0; k0 < K; k0 += 32) {
    __syncthreads();               // all waves done reading previous tile
    gload_lds16(Ap0, Asw);
    gload_lds16(Ap1, Asw + 2048);
    gload_lds16(Bp0, Bsw);
    gload_lds16(Bp1, Bsw + 2048);
    Ap0 += 32; Ap1 += 32; Bp0 += 32; Bp1 += 32;
    __syncthreads();               // drains vmcnt -> tile visible

    bf16x8 af[4], bfr[4];
#pragma unroll
    for (int mb = 0; mb < 4; ++mb)
      af[mb] = ldbf8(As + (wr * 64 + mb * 16 + q) * 32 + g * 8);
#pragma unroll
    for (int nb = 0; nb < 4; ++nb)
      bfr[nb] = ldbf8(Bs + (wc * 64 + nb * 16 + q) * 32 + g * 8);
#pragma unroll
    for (int mb = 0; mb < 4; ++mb)
#pragma unroll
      for (int nb = 0; nb < 4; ++nb)
        acc[mb][nb] = __builtin_amdgcn_mfma_f32_16x16x32_bf16(af[mb], bfr[nb], acc[mb][nb], 0, 0, 0);
  }

#pragma unroll
  for (int mb = 0; mb < 4; ++mb)
#pragma unroll
    for (int nb = 0; nb < 4; ++nb)
#pragma unroll
      for (int r = 0; r < 4; ++r) {
        const int row = row0 + wr * 64 + mb * 16 + g * 4 + r;  // C/D: row=(l>>4)*4+reg
        const int col = col0 + wc * 64 + nb * 16 + q;          //       col=l&15
        const float v = acc[mb][nb][r];
        if (OUT_BF16) ((unsigned short*)Cout)[(size_t)row * ldc + col] = f2bf(v);
        else          ((float*)Cout)[(size_t)row * ldc + col] = v;
      }
}

// ---------------- causal flash attention ----------------
// 4 waves/block, each wave owns 32 Q-rows; KV tiles of 64.
// Swapped QK^T (mfma(K,Q)) -> S^T in regs, softmax mostly lane-local.
// O accumulated transposed (mfma(Vt,P)) -> rescale/normalize lane-local.
__global__ __launch_bounds__(256) void attn_kernel(
    const unsigned short* __restrict__ qkv,  // (B*S) x 3H row-major
    const unsigned short* __restrict__ VtG,  // (B*16*64) x S : V transposed
    unsigned short* __restrict__ O) {        // (B*S) x H row-major
  const int S = 2048, H = 1024, LD = 3072;
  const int wave = threadIdx.x >> 6, lane = threadIdx.x & 63;
  const int g = lane >> 4, q = lane & 15;
  const int h = blockIdx.y, b = blockIdx.z;
  const int qt = (gridDim.x - 1 - blockIdx.x) * 4 + wave;  // longest-first
  const int q0 = qt << 5;

  const unsigned short* Qb = qkv + (size_t)b * S * LD + h * 64;
  const unsigned short* Kb = Qb + H;
  const unsigned short* Vt = VtG + (size_t)(b * 16 + h) * 64 * S;

  __shared__ __align__(16) unsigned short PlAll[4][32 * 64];  // 4KB per wave
  unsigned short* Pl = PlAll[wave];

  // Q fragments held for the whole row-tile
  bf16x8 qf[2][2];
#pragma unroll
  for (int mb = 0; mb < 2; ++mb)
#pragma unroll
    for (int kc = 0; kc < 2; ++kc)
      qf[mb][kc] = ldbf8(Qb + (size_t)(q0 + mb * 16 + q) * LD + kc * 32 + g * 8);

  f32x4 acc[4][2] = {};          // acc[db][mb] = O^T subtile (rows d, cols qrow)
  float m_r[2] = {-1e30f, -1e30f}, l_r[2] = {0.f, 0.f};

  const int nt = (q0 >> 6) + 1;
  for (int t = 0; t < nt; ++t) {
    const int c0 = t << 6;
    const int nbv = min(4, ((q0 + 31 - c0) >> 4) + 1);  // valid 16-col subtiles
    const int kcv = nbv >> 1;                            // valid 32-kv chunks for PV

    // K fragments direct from global (L2-resident)
    bf16x8 kf[4][2];
#pragma unroll
    for (int nb = 0; nb < 4; ++nb) if (nb < nbv)
#pragma unroll
      for (int kc = 0; kc < 2; ++kc)
        kf[nb][kc] = ldbf8(Kb + (size_t)(c0 + nb * 16 + q) * LD + kc * 32 + g * 8);

    // S^T = (K Q^T)/sqrt(dh): lane holds rows kv=nb*16+g*4+r, col qrow=mb*16+q
    f32x4 st[4][2] = {};
#pragma unroll
    for (int kc = 0; kc < 2; ++kc)
#pragma unroll
      for (int nb = 0; nb < 4; ++nb) if (nb < nbv)
#pragma unroll
        for (int mb = 0; mb < 2; ++mb)
          st[nb][mb] = __builtin_amdgcn_mfma_f32_16x16x32_bf16(kf[nb][kc], qf[mb][kc], st[nb][mb], 0, 0, 0);

    // issue V loads early; latency hides under softmax VALU
    bf16x8 vf[4][2];
#pragma unroll
    for (int kc = 0; kc < 2; ++kc) if (kc < kcv)
#pragma unroll
      for (int db = 0; db < 4; ++db)
        vf[db][kc] = ldbf8(Vt + (size_t)(db * 16 + q) * S + c0 + kc * 32 + g * 8);

#pragma unroll
    for (int nb = 0; nb < 4; ++nb) if (nb < nbv)
#pragma unroll
      for (int mb = 0; mb < 2; ++mb)
        st[nb][mb] *= 0.125f;

    if (c0 + 63 > q0) {  // causal mask (only last 1-2 tiles)
#pragma unroll
      for (int nb = 0; nb < 4; ++nb) if (nb < nbv)
#pragma unroll
        for (int mb = 0; mb < 2; ++mb)
#pragma unroll
          for (int r = 0; r < 4; ++r)
            if (c0 + nb * 16 + g * 4 + r > q0 + mb * 16 + q) st[nb][mb][r] = -1e30f;
    }

    // online softmax; per-qrow stats live in lane's q (replicated across g)
    float sf[2];
#pragma unroll
    for (int mb = 0; mb < 2; ++mb) {
      float mx = -1e30f;
#pragma unroll
      for (int nb = 0; nb < 4; ++nb) if (nb < nbv)
        mx = fmaxf(mx, fmaxf(fmaxf(st[nb][mb][0], st[nb][mb][1]),
                             fmaxf(st[nb][mb][2], st[nb][mb][3])));
      mx = fmaxf(mx, __shfl_xor(mx, 16));
      mx = fmaxf(mx, __shfl_xor(mx, 32));
      const float mn = fmaxf(m_r[mb], mx);
      sf[mb] = __expf(m_r[mb] - mn);
      m_r[mb] = mn;
      float rs = 0.f;
      const int rq = mb * 16 + q;
#pragma unroll
      for (int nb = 0; nb < 4; ++nb) if (nb < nbv) {
        ushort4v pw;
#pragma unroll
        for (int r = 0; r < 4; ++r) {
          const float p = __expf(st[nb][mb][r] - mn);
          rs += p;
          pw[r] = f2bf(p);
        }
        // P relayout: Pl[qrow][kv], XOR-swizzled by (q&7) to spread banks
        *(ushort4v*)((char*)Pl + rq * 128 + ((nb * 32 + g * 8) ^ ((q & 7) << 4))) = pw;
      }
      rs += __shfl_xor(rs, 16);
      rs += __shfl_xor(rs, 32);
      l_r[mb] = l_r[mb] * sf[mb] + rs;
    }

    // rescale O^T (cols = qrow = q -> lane-local)
#pragma unroll
    for (int db = 0; db < 4; ++db)
#pragma unroll
      for (int mb = 0; mb < 2; ++mb)
#pragma unroll
        for (int r = 0; r < 4; ++r) acc[db][mb][r] *= sf[mb];

    asm volatile("s_waitcnt lgkmcnt(0)" ::: "memory");  // P writes committed

    // O^T += V^T P : mfma(A=Vt frag, B=P frag)
#pragma unroll
    for (int kc = 0; kc < 2; ++kc) if (kc < kcv) {
      bf16x8 pa[2];
#pragma unroll
      for (int mb = 0; mb < 2; ++mb)
        pa[mb] = ldbf8((const unsigned short*)((const char*)Pl + (mb * 16 + q) * 128 +
                                               ((kc * 64 + g * 16) ^ ((q & 7) << 4))));
#pragma unroll
      for (int db = 0; db < 4; ++db)
#pragma unroll
        for (int mb = 0; mb < 2; ++mb)
          acc[db][mb] = __builtin_amdgcn_mfma_f32_16x16x32_bf16(vf[db][kc], pa[mb], acc[db][mb], 0, 0, 0);
    }
  }

  // epilogue: O[qrow][d] = O^T[d][qrow]/l ; lane packs 4 consecutive d (8B store)
#pragma unroll
  for (int mb = 0; mb < 2; ++mb) {
    const float inv = 1.f / l_r[mb];
    const size_t rowbase = (size_t)(b * S + q0 + mb * 16 + q) * H + h * 64;
#pragma unroll
    for (int db = 0; db < 4; ++db) {
      ushort4v o;
#pragma unroll
      for (int r = 0; r < 4; ++r) o[r] = f2bf(acc[db][mb][r] * inv);
      *(ushort4v*)(O + rowbase + db * 16 + g * 4) = o;
    }
  }
}

extern "C" void kernel_launch(void* const* d_in, const int* in_sizes, int n_in,
                              void* d_out, int out_size, void* d_ws, size_t ws_size,
                              hipStream_t stream) {
  const float* x     = (const float*)d_in[0];
  const float* w_qkv = (const float*)d_in[1];
  const float* w_out = (const float*)d_in[2];
  const int B = 2, S = 2048, H = 1024;
  const int M = B * S;  // 4096

  // workspace layout (ushort elements), total 48 MB:
  unsigned short* xb    = (unsigned short*)d_ws;        // M*H   (8 MB)  -> reused as VtG
  unsigned short* wqkvT = xb + (size_t)M * H;           // 3H*H  (6 MB)
  unsigned short* woutT = wqkvT + (size_t)3 * H * H;    // H*H   (2 MB)
  unsigned short* qkvb  = woutT + (size_t)H * H;        // M*3H (24 MB)
  unsigned short* Ob    = qkvb + (size_t)M * 3 * H;     // M*H   (8 MB)
  unsigned short* VtG   = xb;  // x-bf16 dead after QKV GEMM; reuse for V^T

  cvt_f32_bf16_kernel<<<1024, 256, 0, stream>>>(x, xb, (M * H) / 4);
  transpose_cvt_kernel<<<dim3((3 * H) / 32, H / 32), 256, 0, stream>>>(w_qkv, wqkvT, H, 3 * H);
  transpose_cvt_kernel<<<dim3(H / 32, H / 32), 256, 0, stream>>>(w_out, woutT, H, H);

  // qkv = x @ w_qkv  (bf16 out, feeds attention)
  gemm_bt_kernel<true><<<dim3(M / 128, (3 * H) / 128), 256, 0, stream>>>(
      xb, wqkvT, qkvb, M, 3 * H, H, H, H, 3 * H);

  // V -> (b,h,d,s) transposed layout (PV B-operand becomes direct 16B loads)
  v_transpose_kernel<<<dim3(S / 32, 32), 256, 0, stream>>>(qkvb, VtG);

  // causal multi-head attention
  attn_kernel<<<dim3(S / 128, 16, B), 256, 0, stream>>>(qkvb, VtG, Ob);

  // out = attn @ w_out (fp32 out)
  gemm_bt_kernel<false><<<dim3(M / 128, H / 128), 256, 0, stream>>>(
      Ob, woutT, d_out, M, H, H, H, H, H);
}

// Round 3
// 169.649 us; speedup vs baseline: 1.7228x; 1.1744x over previous
//
#include <hip/hip_runtime.h>

#define DEVINL __device__ __forceinline__

typedef __attribute__((ext_vector_type(8))) __bf16          bf16x8;
typedef __attribute__((ext_vector_type(4))) float           f32x4;
typedef __attribute__((ext_vector_type(8))) unsigned short  ushort8;
typedef __attribute__((ext_vector_type(4))) unsigned short  ushort4v;
typedef __attribute__((ext_vector_type(4))) float           float4v;

DEVINL unsigned short f2bf(float f) {
  unsigned int u = __float_as_uint(f);
  u += 0x7fffu + ((u >> 16) & 1u);   // round-to-nearest-even
  return (unsigned short)(u >> 16);
}

DEVINL bf16x8 ldbf8(const unsigned short* p) {
  return __builtin_bit_cast(bf16x8, *(const ushort8*)p);
}

// async global->LDS, 16B per lane; LDS dest = wave-uniform base + lane*16
DEVINL void gload_lds16(const unsigned short* g, unsigned short* l) {
  __builtin_amdgcn_global_load_lds((const __attribute__((address_space(1))) void*)g,
                                   (__attribute__((address_space(3))) void*)l, 16, 0, 0);
}

// ---------------- fp32 -> bf16 elementwise ----------------
__global__ __launch_bounds__(256) void cvt_f32_bf16_kernel(
    const float* __restrict__ in, unsigned short* __restrict__ out, int n4) {
  int i = blockIdx.x * 256 + threadIdx.x;
  const int stride = gridDim.x * 256;
  for (; i < n4; i += stride) {
    float4v v = *(const float4v*)(in + (size_t)4 * i);
    ushort4v o;
    o[0] = f2bf(v[0]); o[1] = f2bf(v[1]); o[2] = f2bf(v[2]); o[3] = f2bf(v[3]);
    *(ushort4v*)(out + (size_t)4 * i) = o;
  }
}

// ---------------- fp32 (RxC) -> bf16 transposed (CxR) ----------------
__global__ __launch_bounds__(256) void transpose_cvt_kernel(
    const float* __restrict__ in, unsigned short* __restrict__ out, int R, int C) {
  __shared__ float tile[32][33];
  const int tx = threadIdx.x & 31, ty = threadIdx.x >> 5;
  const int r0 = blockIdx.y << 5, c0 = blockIdx.x << 5;
#pragma unroll
  for (int i = 0; i < 32; i += 8)
    tile[ty + i][tx] = in[(size_t)(r0 + ty + i) * C + (c0 + tx)];
  __syncthreads();
#pragma unroll
  for (int i = 0; i < 32; i += 8)
    out[(size_t)(c0 + ty + i) * R + (r0 + tx)] = f2bf(tile[tx][ty + i]);
}

// ---------------- bf16 V transpose: qkv V-third -> Vt[(b,h,d)][s] ----------------
__global__ __launch_bounds__(256) void v_transpose_kernel(
    const unsigned short* __restrict__ qkv, unsigned short* __restrict__ VtG) {
  const int S = 2048, LD = 3072;
  const int s0 = blockIdx.x << 5;
  const int bh = blockIdx.y;           // b*16 + h
  const int b = bh >> 4, h = bh & 15;
  __shared__ __align__(16) unsigned short T[32][72];  // 16B-aligned rows
  const int t = threadIdx.x;
  {
    const int s = t >> 3, d0 = (t & 7) << 3;
    *(ushort8*)&T[s][d0] =
        *(const ushort8*)(qkv + ((size_t)(b * S) + s0 + s) * LD + 2048 + h * 64 + d0);
  }
  __syncthreads();
  {
    const int d = t >> 2, sc = (t & 3) << 3;
    ushort8 o;
#pragma unroll
    for (int e = 0; e < 8; ++e) o[e] = T[sc + e][d];
    *(ushort8*)(VtG + ((size_t)bh * 64 + d) * S + s0 + sc) = o;
  }
}

// ---------------- bf16 GEMM: C = A(MxK) * Bt(NxK)^T ----------------
// 128x128 tile, BK=32, 4 waves (2x2), global_load_lds staging (m97 structure).
template <bool OUT_BF16>
__global__ __launch_bounds__(256) void gemm_bt_kernel(
    const unsigned short* __restrict__ A,   // M x K, lda
    const unsigned short* __restrict__ Bt,  // N x K, ldb
    void* __restrict__ Cout,                // M x N, ldc
    int M, int N, int K, int lda, int ldb, int ldc) {
  __shared__ __align__(16) unsigned short As[128 * 32];
  __shared__ __align__(16) unsigned short Bs[128 * 32];
  const int tid = threadIdx.x;
  const int lane = tid & 63, wave = tid >> 6;
  const int wr = wave >> 1, wc = wave & 1;
  const int g = lane >> 4, q = lane & 15;
  const int row0 = blockIdx.x << 7, col0 = blockIdx.y << 7;

  const int srow = tid >> 2, skcol = (tid & 3) << 3;
  const unsigned short* Ap0 = A + (size_t)(row0 + srow) * lda + skcol;
  const unsigned short* Ap1 = Ap0 + (size_t)64 * lda;
  const unsigned short* Bp0 = Bt + (size_t)(col0 + srow) * ldb + skcol;
  const unsigned short* Bp1 = Bp0 + (size_t)64 * ldb;
  unsigned short* Asw = As + wave * 512;  // wave-uniform LDS base (w*1024 B)
  unsigned short* Bsw = Bs + wave * 512;

  f32x4 acc[4][4] = {};

  for (int k0 = 0; k0 < K; k0 += 32) {
    __syncthreads();               // all waves done reading previous tile
    gload_lds16(Ap0, Asw);
    gload_lds16(Ap1, Asw + 2048);
    gload_lds16(Bp0, Bsw);
    gload_lds16(Bp1, Bsw + 2048);
    Ap0 += 32; Ap1 += 32; Bp0 += 32; Bp1 += 32;
    __syncthreads();               // drains vmcnt -> tile visible

    bf16x8 af[4], bfr[4];
#pragma unroll
    for (int mb = 0; mb < 4; ++mb)
      af[mb] = ldbf8(As + (wr * 64 + mb * 16 + q) * 32 + g * 8);
#pragma unroll
    for (int nb = 0; nb < 4; ++nb)
      bfr[nb] = ldbf8(Bs + (wc * 64 + nb * 16 + q) * 32 + g * 8);
#pragma unroll
    for (int mb = 0; mb < 4; ++mb)
#pragma unroll
      for (int nb = 0; nb < 4; ++nb)
        acc[mb][nb] = __builtin_amdgcn_mfma_f32_16x16x32_bf16(af[mb], bfr[nb], acc[mb][nb], 0, 0, 0);
  }

#pragma unroll
  for (int mb = 0; mb < 4; ++mb)
#pragma unroll
    for (int nb = 0; nb < 4; ++nb)
#pragma unroll
      for (int r = 0; r < 4; ++r) {
        const int row = row0 + wr * 64 + mb * 16 + g * 4 + r;  // C/D: row=(l>>4)*4+reg
        const int col = col0 + wc * 64 + nb * 16 + q;          //       col=l&15
        const float v = acc[mb][nb][r];
        if (OUT_BF16) ((unsigned short*)Cout)[(size_t)row * ldc + col] = f2bf(v);
        else          ((float*)Cout)[(size_t)row * ldc + col] = v;
      }
}

// ---------------- causal flash attention ----------------
// Block = 4 waves x 32 q-rows (128 rows). K/V tiles (64 kv) cooperatively
// staged in LDS, double-buffered via global_load_lds + counted vmcnt(4) +
// raw s_barrier (prefetch never drained). XOR-swizzled K/V LDS rows.
// Swapped QK^T -> S^T in regs; O accumulated transposed; softmax lane-local.
__global__ __launch_bounds__(256) void attn_kernel(
    const unsigned short* __restrict__ qkv,  // (B*S) x 3H row-major
    const unsigned short* __restrict__ VtG,  // (B*16*64) x S : V transposed
    unsigned short* __restrict__ O) {        // (B*S) x H row-major
  const int S = 2048, H = 1024, LD = 3072;
  const int wave = threadIdx.x >> 6, lane = threadIdx.x & 63;
  const int g = lane >> 4, q = lane & 15;
  const int h = blockIdx.y, b = blockIdx.z;
  const int qc = gridDim.x - 1 - blockIdx.x;   // longest-first
  const int q0w = qc * 128 + wave * 32;        // this wave's 32 q-rows

  const unsigned short* Qb = qkv + (size_t)b * S * LD + h * 64;
  const unsigned short* Kb = Qb + H;
  const unsigned short* Vt = VtG + (size_t)(b * 16 + h) * 64 * S;

  __shared__ __align__(16) unsigned short Ks[2][64 * 64];   // [kv row][d], swizzled
  __shared__ __align__(16) unsigned short Vs[2][64 * 64];   // [d][kv], swizzled
  __shared__ __align__(16) unsigned short PlAll[4][32 * 64];
  unsigned short* Pl = PlAll[wave];

  // staging geometry: per wave 4 x gload_lds16 per tile (2 K rows-halves, 2 V)
  const int srow = lane >> 3;                        // 0..7 row within wave chunk
  const int srcg = ((lane & 7) ^ srow) << 3;         // pre-swizzled granule (shorts)
  const int wrow = wave * 8 + srow;                  // 0..31 row within half-tile

  // Q fragments held for the whole row-tile
  bf16x8 qf[2][2];
#pragma unroll
  for (int mb = 0; mb < 2; ++mb)
#pragma unroll
    for (int kc = 0; kc < 2; ++kc)
      qf[mb][kc] = ldbf8(Qb + (size_t)(q0w + mb * 16 + q) * LD + kc * 32 + g * 8);

  f32x4 acc[4][2] = {};          // acc[db][mb] = O^T subtile (rows d, cols qrow)
  float m_r[2] = {-1e30f, -1e30f}, l_r[2] = {0.f, 0.f};

  const int ntb = qc * 2 + 2;    // KV tiles this block processes
  int cur = 0;

  // prologue: stage tile 0 into buffer 0
  {
    gload_lds16(Kb + (size_t)wrow * LD + srcg,        Ks[0] + wave * 512);
    gload_lds16(Kb + (size_t)(32 + wrow) * LD + srcg, Ks[0] + 2048 + wave * 512);
    gload_lds16(Vt + (size_t)wrow * S + srcg,         Vs[0] + wave * 512);
    gload_lds16(Vt + (size_t)(32 + wrow) * S + srcg,  Vs[0] + 2048 + wave * 512);
  }

  const int swq = (q & 7) << 3;  // read-side XOR (shorts)

  for (int t = 0; t < ntb; ++t) {
    if (t + 1 < ntb) {           // issue next tile's loads; stay in flight
      const int c1 = (t + 1) << 6;
      unsigned short* KsN = Ks[cur ^ 1];
      unsigned short* VsN = Vs[cur ^ 1];
      gload_lds16(Kb + (size_t)(c1 + wrow) * LD + srcg,      KsN + wave * 512);
      gload_lds16(Kb + (size_t)(c1 + 32 + wrow) * LD + srcg, KsN + 2048 + wave * 512);
      gload_lds16(Vt + (size_t)wrow * S + c1 + srcg,         VsN + wave * 512);
      gload_lds16(Vt + (size_t)(32 + wrow) * S + c1 + srcg,  VsN + 2048 + wave * 512);
      asm volatile("s_waitcnt vmcnt(4)" ::: "memory");   // tile t resident
    } else {
      asm volatile("s_waitcnt vmcnt(0)" ::: "memory");
    }
    __builtin_amdgcn_s_barrier();  // all waves' stage(t) visible

    const int c0 = t << 6;
    const unsigned short* KsC = Ks[cur];
    const unsigned short* VsC = Vs[cur];

    if (c0 <= q0w + 31) {  // wave has unmasked rows in this tile
      const int nbv = min(4, ((q0w + 31 - c0) >> 4) + 1);  // valid 16-col subtiles
      const int kcv = nbv >> 1;                            // valid 32-kv chunks

      bf16x8 kf[4][2];
#pragma unroll
      for (int nb = 0; nb < 4; ++nb) if (nb < nbv)
#pragma unroll
        for (int kc = 0; kc < 2; ++kc)
          kf[nb][kc] = ldbf8(KsC + (nb * 16 + q) * 64 + ((kc * 32 + g * 8) ^ swq));

      // S^T = (K Q^T)/sqrt(dh): lane holds rows kv=nb*16+g*4+r, col qrow=mb*16+q
      f32x4 st[4][2] = {};
#pragma unroll
      for (int kc = 0; kc < 2; ++kc)
#pragma unroll
        for (int nb = 0; nb < 4; ++nb) if (nb < nbv)
#pragma unroll
          for (int mb = 0; mb < 2; ++mb)
            st[nb][mb] = __builtin_amdgcn_mfma_f32_16x16x32_bf16(kf[nb][kc], qf[mb][kc], st[nb][mb], 0, 0, 0);

#pragma unroll
      for (int nb = 0; nb < 4; ++nb) if (nb < nbv)
#pragma unroll
        for (int mb = 0; mb < 2; ++mb)
          st[nb][mb] *= 0.125f;

      if (c0 + 63 > q0w) {  // causal mask (only last tiles)
#pragma unroll
        for (int nb = 0; nb < 4; ++nb) if (nb < nbv)
#pragma unroll
          for (int mb = 0; mb < 2; ++mb)
#pragma unroll
            for (int r = 0; r < 4; ++r)
              if (c0 + nb * 16 + g * 4 + r > q0w + mb * 16 + q) st[nb][mb][r] = -1e30f;
      }

      // online softmax; per-qrow stats live in lane's q (replicated across g)
      float sf[2];
#pragma unroll
      for (int mb = 0; mb < 2; ++mb) {
        float mx = -1e30f;
#pragma unroll
        for (int nb = 0; nb < 4; ++nb) if (nb < nbv)
          mx = fmaxf(mx, fmaxf(fmaxf(st[nb][mb][0], st[nb][mb][1]),
                               fmaxf(st[nb][mb][2], st[nb][mb][3])));
        mx = fmaxf(mx, __shfl_xor(mx, 16));
        mx = fmaxf(mx, __shfl_xor(mx, 32));
        const float mn = fmaxf(m_r[mb], mx);
        sf[mb] = __expf(m_r[mb] - mn);
        m_r[mb] = mn;
        float rs = 0.f;
        const int rq = mb * 16 + q;
#pragma unroll
        for (int nb = 0; nb < 4; ++nb) if (nb < nbv) {
          ushort4v pw;
#pragma unroll
          for (int r = 0; r < 4; ++r) {
            const float p = __expf(st[nb][mb][r] - mn);
            rs += p;
            pw[r] = f2bf(p);
          }
          *(ushort4v*)((char*)Pl + rq * 128 + ((nb * 32 + g * 8) ^ ((q & 7) << 4))) = pw;
        }
        rs += __shfl_xor(rs, 16);
        rs += __shfl_xor(rs, 32);
        l_r[mb] = l_r[mb] * sf[mb] + rs;
      }

      // rescale O^T (cols = qrow = q -> lane-local)
#pragma unroll
      for (int db = 0; db < 4; ++db)
#pragma unroll
        for (int mb = 0; mb < 2; ++mb)
#pragma unroll
          for (int r = 0; r < 4; ++r) acc[db][mb][r] *= sf[mb];

      asm volatile("s_waitcnt lgkmcnt(0)" ::: "memory");  // P writes committed

      // O^T += V^T P : mfma(A=Vt frag, B=P frag)
#pragma unroll
      for (int kc = 0; kc < 2; ++kc) if (kc < kcv) {
        bf16x8 vfk[4], pa[2];
#pragma unroll
        for (int db = 0; db < 4; ++db)
          vfk[db] = ldbf8(VsC + (db * 16 + q) * 64 + ((kc * 32 + g * 8) ^ swq));
#pragma unroll
        for (int mb = 0; mb < 2; ++mb)
          pa[mb] = ldbf8((const unsigned short*)((const char*)Pl + (mb * 16 + q) * 128 +
                                                 ((kc * 64 + g * 16) ^ ((q & 7) << 4))));
#pragma unroll
        for (int db = 0; db < 4; ++db)
#pragma unroll
          for (int mb = 0; mb < 2; ++mb)
            acc[db][mb] = __builtin_amdgcn_mfma_f32_16x16x32_bf16(vfk[db], pa[mb], acc[db][mb], 0, 0, 0);
      }
    }

    __builtin_amdgcn_s_barrier();  // all waves done reading buf[cur]
    cur ^= 1;
  }

  // epilogue: O[qrow][d] = O^T[d][qrow]/l ; lane packs 4 consecutive d (8B store)
#pragma unroll
  for (int mb = 0; mb < 2; ++mb) {
    const float inv = 1.f / l_r[mb];
    const size_t rowbase = (size_t)(b * S + q0w + mb * 16 + q) * H + h * 64;
#pragma unroll
    for (int db = 0; db < 4; ++db) {
      ushort4v o;
#pragma unroll
      for (int r = 0; r < 4; ++r) o[r] = f2bf(acc[db][mb][r] * inv);
      *(ushort4v*)(O + rowbase + db * 16 + g * 4) = o;
    }
  }
}

extern "C" void kernel_launch(void* const* d_in, const int* in_sizes, int n_in,
                              void* d_out, int out_size, void* d_ws, size_t ws_size,
                              hipStream_t stream) {
  const float* x     = (const float*)d_in[0];
  const float* w_qkv = (const float*)d_in[1];
  const float* w_out = (const float*)d_in[2];
  const int B = 2, S = 2048, H = 1024;
  const int M = B * S;  // 4096

  // workspace layout (ushort elements), total 48 MB:
  unsigned short* xb    = (unsigned short*)d_ws;        // M*H   (8 MB)  -> reused as VtG
  unsigned short* wqkvT = xb + (size_t)M * H;           // 3H*H  (6 MB)
  unsigned short* woutT = wqkvT + (size_t)3 * H * H;    // H*H   (2 MB)
  unsigned short* qkvb  = woutT + (size_t)H * H;        // M*3H (24 MB)
  unsigned short* Ob    = qkvb + (size_t)M * 3 * H;     // M*H   (8 MB)
  unsigned short* VtG   = xb;  // x-bf16 dead after QKV GEMM; reuse for V^T

  cvt_f32_bf16_kernel<<<1024, 256, 0, stream>>>(x, xb, (M * H) / 4);
  transpose_cvt_kernel<<<dim3((3 * H) / 32, H / 32), 256, 0, stream>>>(w_qkv, wqkvT, H, 3 * H);
  transpose_cvt_kernel<<<dim3(H / 32, H / 32), 256, 0, stream>>>(w_out, woutT, H, H);

  // qkv = x @ w_qkv  (bf16 out, feeds attention)
  gemm_bt_kernel<true><<<dim3(M / 128, (3 * H) / 128), 256, 0, stream>>>(
      xb, wqkvT, qkvb, M, 3 * H, H, H, H, 3 * H);

  // V -> (b,h,d,s) transposed layout (PV B-operand becomes direct 16B loads)
  v_transpose_kernel<<<dim3(S / 32, 32), 256, 0, stream>>>(qkvb, VtG);

  // causal multi-head attention
  attn_kernel<<<dim3(S / 128, 16, B), 256, 0, stream>>>(qkvb, VtG, Ob);

  // out = attn @ w_out (fp32 out)
  gemm_bt_kernel<false><<<dim3(M / 128, H / 128), 256, 0, stream>>>(
      Ob, woutT, d_out, M, H, H, H, H, H);
}

// Round 4
// 149.368 us; speedup vs baseline: 1.9567x; 1.1358x over previous
//
#include <hip/hip_runtime.h>

#define DEVINL __device__ __forceinline__

typedef __attribute__((ext_vector_type(8)))  __bf16         bf16x8;
typedef __attribute__((ext_vector_type(4)))  float          f32x4;
typedef __attribute__((ext_vector_type(16))) float          f32x16;
typedef __attribute__((ext_vector_type(8)))  unsigned short ushort8;
typedef __attribute__((ext_vector_type(4)))  unsigned short ushort4v;
typedef __attribute__((ext_vector_type(4)))  unsigned int   uint4v;
typedef __attribute__((ext_vector_type(4)))  float          float4v;

DEVINL unsigned short f2bf(float f) {
  unsigned int u = __float_as_uint(f);
  u += 0x7fffu + ((u >> 16) & 1u);   // round-to-nearest-even
  return (unsigned short)(u >> 16);
}

DEVINL bf16x8 ldbf8(const unsigned short* p) {
  return __builtin_bit_cast(bf16x8, *(const ushort8*)p);
}

DEVINL unsigned cvtpk_bf16(float lo, float hi) {  // dst.lo16=bf16(lo), dst.hi16=bf16(hi)
  unsigned r;
  asm("v_cvt_pk_bf16_f32 %0, %1, %2" : "=v"(r) : "v"(lo), "v"(hi));
  return r;
}

// async global->LDS, 16B per lane; LDS dest = wave-uniform base + lane*16
DEVINL void gload_lds16(const unsigned short* g, unsigned short* l) {
  __builtin_amdgcn_global_load_lds((const __attribute__((address_space(1))) void*)g,
                                   (__attribute__((address_space(3))) void*)l, 16, 0, 0);
}

// ---------------- fp32 -> bf16 elementwise ----------------
__global__ __launch_bounds__(256) void cvt_f32_bf16_kernel(
    const float* __restrict__ in, unsigned short* __restrict__ out, int n4) {
  int i = blockIdx.x * 256 + threadIdx.x;
  const int stride = gridDim.x * 256;
  for (; i < n4; i += stride) {
    float4v v = *(const float4v*)(in + (size_t)4 * i);
    ushort4v o;
    o[0] = f2bf(v[0]); o[1] = f2bf(v[1]); o[2] = f2bf(v[2]); o[3] = f2bf(v[3]);
    *(ushort4v*)(out + (size_t)4 * i) = o;
  }
}

// ---------------- fp32 (RxC) -> bf16 transposed (CxR) ----------------
__global__ __launch_bounds__(256) void transpose_cvt_kernel(
    const float* __restrict__ in, unsigned short* __restrict__ out, int R, int C) {
  __shared__ float tile[32][33];
  const int tx = threadIdx.x & 31, ty = threadIdx.x >> 5;
  const int r0 = blockIdx.y << 5, c0 = blockIdx.x << 5;
#pragma unroll
  for (int i = 0; i < 32; i += 8)
    tile[ty + i][tx] = in[(size_t)(r0 + ty + i) * C + (c0 + tx)];
  __syncthreads();
#pragma unroll
  for (int i = 0; i < 32; i += 8)
    out[(size_t)(c0 + ty + i) * R + (r0 + tx)] = f2bf(tile[tx][ty + i]);
}

// ---------------- bf16 V transpose: qkv V-third -> Vt[(b,h,d)][s] ----------------
__global__ __launch_bounds__(256) void v_transpose_kernel(
    const unsigned short* __restrict__ qkv, unsigned short* __restrict__ VtG) {
  const int S = 2048, LD = 3072;
  const int s0 = blockIdx.x << 5;
  const int bh = blockIdx.y;           // b*16 + h
  const int b = bh >> 4, h = bh & 15;
  __shared__ __align__(16) unsigned short T[32][72];  // 16B-aligned rows
  const int t = threadIdx.x;
  {
    const int s = t >> 3, d0 = (t & 7) << 3;
    *(ushort8*)&T[s][d0] =
        *(const ushort8*)(qkv + ((size_t)(b * S) + s0 + s) * LD + 2048 + h * 64 + d0);
  }
  __syncthreads();
  {
    const int d = t >> 2, sc = (t & 3) << 3;
    ushort8 o;
#pragma unroll
    for (int e = 0; e < 8; ++e) o[e] = T[sc + e][d];
    *(ushort8*)(VtG + ((size_t)bh * 64 + d) * S + s0 + sc) = o;
  }
}

// ---------------- bf16 GEMM: C = A(MxK) * Bt(NxK)^T ----------------
// 128x128 tile, BK=32, 4 waves (2x2), global_load_lds staging (m97 structure).
template <bool OUT_BF16>
__global__ __launch_bounds__(256) void gemm_bt_kernel(
    const unsigned short* __restrict__ A,   // M x K, lda
    const unsigned short* __restrict__ Bt,  // N x K, ldb
    void* __restrict__ Cout,                // M x N, ldc
    int M, int N, int K, int lda, int ldb, int ldc) {
  __shared__ __align__(16) unsigned short As[128 * 32];
  __shared__ __align__(16) unsigned short Bs[128 * 32];
  const int tid = threadIdx.x;
  const int lane = tid & 63, wave = tid >> 6;
  const int wr = wave >> 1, wc = wave & 1;
  const int g = lane >> 4, q = lane & 15;
  const int row0 = blockIdx.x << 7, col0 = blockIdx.y << 7;

  const int srow = tid >> 2, skcol = (tid & 3) << 3;
  const unsigned short* Ap0 = A + (size_t)(row0 + srow) * lda + skcol;
  const unsigned short* Ap1 = Ap0 + (size_t)64 * lda;
  const unsigned short* Bp0 = Bt + (size_t)(col0 + srow) * ldb + skcol;
  const unsigned short* Bp1 = Bp0 + (size_t)64 * ldb;
  unsigned short* Asw = As + wave * 512;  // wave-uniform LDS base (w*1024 B)
  unsigned short* Bsw = Bs + wave * 512;

  f32x4 acc[4][4] = {};

  for (int k0 = 0; k0 < K; k0 += 32) {
    __syncthreads();               // all waves done reading previous tile
    gload_lds16(Ap0, Asw);
    gload_lds16(Ap1, Asw + 2048);
    gload_lds16(Bp0, Bsw);
    gload_lds16(Bp1, Bsw + 2048);
    Ap0 += 32; Ap1 += 32; Bp0 += 32; Bp1 += 32;
    __syncthreads();               // drains vmcnt -> tile visible

    bf16x8 af[4], bfr[4];
#pragma unroll
    for (int mb = 0; mb < 4; ++mb)
      af[mb] = ldbf8(As + (wr * 64 + mb * 16 + q) * 32 + g * 8);
#pragma unroll
    for (int nb = 0; nb < 4; ++nb)
      bfr[nb] = ldbf8(Bs + (wc * 64 + nb * 16 + q) * 32 + g * 8);
#pragma unroll
    for (int mb = 0; mb < 4; ++mb)
#pragma unroll
      for (int nb = 0; nb < 4; ++nb)
        acc[mb][nb] = __builtin_amdgcn_mfma_f32_16x16x32_bf16(af[mb], bfr[nb], acc[mb][nb], 0, 0, 0);
  }

#pragma unroll
  for (int mb = 0; mb < 4; ++mb)
#pragma unroll
    for (int nb = 0; nb < 4; ++nb)
#pragma unroll
      for (int r = 0; r < 4; ++r) {
        const int row = row0 + wr * 64 + mb * 16 + g * 4 + r;  // C/D: row=(l>>4)*4+reg
        const int col = col0 + wc * 64 + nb * 16 + q;          //       col=l&15
        const float v = acc[mb][nb][r];
        if (OUT_BF16) ((unsigned short*)Cout)[(size_t)row * ldc + col] = f2bf(v);
        else          ((float*)Cout)[(size_t)row * ldc + col] = v;
      }
}

// ---------------- causal flash attention (32x32 MFMA, in-register P) ----------------
// Block = 4 waves x 32 q-rows. K/V staged in LDS (dbuf, counted vmcnt, raw barrier,
// XOR swizzle). Swapped QK^T -> S^T; C/D 32x32 layout has a 2-group lane split, so
// P relayout = cvt_pk_bf16 + permlane32_swap (no LDS). Defer-max online softmax:
// common path has zero cross-lane ops; l kept per-lane-partial until epilogue.
__global__ __launch_bounds__(256, 2) void attn_kernel(
    const unsigned short* __restrict__ qkv,  // (B*S) x 3H row-major
    const unsigned short* __restrict__ VtG,  // (B*16*64) x S : V transposed
    unsigned short* __restrict__ O) {        // (B*S) x H row-major
  const int S = 2048, H = 1024, LD = 3072;
  const int wave = threadIdx.x >> 6, lane = threadIdx.x & 63;
  const int c = lane & 31, hh = lane >> 5;
  const int h = blockIdx.y, b = blockIdx.z;
  const int qc = gridDim.x - 1 - blockIdx.x;   // longest-first
  const int q0w = qc * 128 + wave * 32;        // this wave's 32 q-rows

  const unsigned short* Qb = qkv + (size_t)b * S * LD + h * 64;
  const unsigned short* Kb = Qb + H;
  const unsigned short* Vt = VtG + (size_t)(b * 16 + h) * 64 * S;

  __shared__ __align__(16) unsigned short Ks[2][64 * 64];   // [kv][d], swizzled
  __shared__ __align__(16) unsigned short Vs[2][64 * 64];   // [d][kv], swizzled

  // staging geometry: 4 x gload_lds16 per wave per tile
  const int srow = lane >> 3;                        // 0..7
  const int srcg = ((lane & 7) ^ srow) << 3;         // pre-swizzled granule (shorts)
  const int wrow = wave * 8 + srow;                  // 0..31

  // prologue: stage tile 0 into buffer 0 (issued before Q loads)
  gload_lds16(Kb + (size_t)wrow * LD + srcg,        Ks[0] + wave * 512);
  gload_lds16(Kb + (size_t)(32 + wrow) * LD + srcg, Ks[0] + 2048 + wave * 512);
  gload_lds16(Vt + (size_t)wrow * S + srcg,         Vs[0] + wave * 512);
  gload_lds16(Vt + (size_t)(32 + wrow) * S + srcg,  Vs[0] + 2048 + wave * 512);

  // Q fragments: lane holds Q[q0w+c][kc*16 + hh*8 + 0..7]
  bf16x8 qf[4];
#pragma unroll
  for (int kc = 0; kc < 4; ++kc)
    qf[kc] = ldbf8(Qb + (size_t)(q0w + c) * LD + kc * 16 + hh * 8);

  f32x16 acc[2] = {};            // O^T: row d = db*32+(r&3)+8(r>>2)+4hh, col = q0w+c
  float m_r = -1e30f, l_r = 0.f; // m uniform across hh pair; l per-lane partial

  const int ntb = qc * 2 + 2;    // KV tiles this block processes
  int cur = 0;
  const int swz = (c & 7) << 3;  // read-side XOR (shorts)

  for (int t = 0; t < ntb; ++t) {
    if (t + 1 < ntb) {           // issue next tile's loads; stay in flight
      const int c1 = (t + 1) << 6;
      unsigned short* KsN = Ks[cur ^ 1];
      unsigned short* VsN = Vs[cur ^ 1];
      gload_lds16(Kb + (size_t)(c1 + wrow) * LD + srcg,      KsN + wave * 512);
      gload_lds16(Kb + (size_t)(c1 + 32 + wrow) * LD + srcg, KsN + 2048 + wave * 512);
      gload_lds16(Vt + (size_t)wrow * S + c1 + srcg,         VsN + wave * 512);
      gload_lds16(Vt + (size_t)(32 + wrow) * S + c1 + srcg,  VsN + 2048 + wave * 512);
      asm volatile("s_waitcnt vmcnt(4)" ::: "memory");   // tile t resident
    } else {
      asm volatile("s_waitcnt vmcnt(0)" ::: "memory");
    }
    __builtin_amdgcn_s_barrier();  // all waves' stage(t) visible

    const int c0 = t << 6;
    const unsigned short* KsC = Ks[cur];
    const unsigned short* VsC = Vs[cur];

    if (c0 <= q0w + 31) {  // wave has unmasked rows in this tile
      int nv = ((q0w + 31 - c0) >> 5) + 1; if (nv > 2) nv = 2;  // valid 32-kv chunks

      // K fragments: A-operand rows kv = n*32+c, k = kc*16+hh*8
      bf16x8 kf[2][4];
#pragma unroll
      for (int n = 0; n < 2; ++n) if (n < nv)
#pragma unroll
        for (int kc = 0; kc < 4; ++kc)
          kf[n][kc] = ldbf8(KsC + (n * 32 + c) * 64 + ((kc * 16 + hh * 8) ^ swz));

      // S^T = K Q^T : st[n] rows kv, cols qrow
      f32x16 st[2] = {};
#pragma unroll
      for (int n = 0; n < 2; ++n) if (n < nv)
#pragma unroll
        for (int kc = 0; kc < 4; ++kc)
          st[n] = __builtin_amdgcn_mfma_f32_32x32x16_bf16(kf[n][kc], qf[kc], st[n], 0, 0, 0);

      // V fragments early (latency hides under softmax): rows d = db*32+c
      bf16x8 vf[2][4];
#pragma unroll
      for (int db = 0; db < 2; ++db)
#pragma unroll
        for (int kk = 0; kk < 4; ++kk) if (kk < 2 * nv)
          vf[db][kk] = ldbf8(VsC + (db * 32 + c) * 64 + ((kk * 16 + hh * 8) ^ swz));

      if (c0 + 63 > q0w) {  // causal mask (diag region only)
#pragma unroll
        for (int n = 0; n < 2; ++n) if (n < nv)
#pragma unroll
          for (int r = 0; r < 16; ++r) {
            const int kv = c0 + n * 32 + (r & 3) + 8 * (r >> 2) + 4 * hh;
            if (kv > q0w + c) st[n][r] = -1e30f;
          }
      }

      // defer-max online softmax (raw-score domain; 64 raw = 8 post-scale)
      float pmax = -1e30f;
#pragma unroll
      for (int n = 0; n < 2; ++n) if (n < nv)
#pragma unroll
        for (int r = 0; r < 16; ++r) pmax = fmaxf(pmax, st[n][r]);
      if (!__all(pmax <= m_r + 64.f)) {   // rare: update running max, rescale
        pmax = fmaxf(pmax, __shfl_xor(pmax, 32));
        const float mn = fmaxf(m_r, pmax);
        const float sf = __expf((m_r - mn) * 0.125f);
        m_r = mn; l_r *= sf;
#pragma unroll
        for (int db = 0; db < 2; ++db) acc[db] *= sf;
      }
      const float m8 = m_r * 0.125f;
#pragma unroll
      for (int n = 0; n < 2; ++n) if (n < nv)
#pragma unroll
        for (int r = 0; r < 16; ++r) {
          const float p = __expf(fmaf(st[n][r], 0.125f, -m8));
          st[n][r] = p;
          l_r += p;
        }

      // P relayout in-register: cvt_pk pairs then permlane32_swap
      bf16x8 pa[4];
#pragma unroll
      for (int n = 0; n < 2; ++n) if (n < nv) {
        unsigned T0 = cvtpk_bf16(st[n][0],  st[n][1]);
        unsigned T1 = cvtpk_bf16(st[n][2],  st[n][3]);
        unsigned T2 = cvtpk_bf16(st[n][4],  st[n][5]);
        unsigned T3 = cvtpk_bf16(st[n][6],  st[n][7]);
        unsigned T4 = cvtpk_bf16(st[n][8],  st[n][9]);
        unsigned T5 = cvtpk_bf16(st[n][10], st[n][11]);
        unsigned T6 = cvtpk_bf16(st[n][12], st[n][13]);
        unsigned T7 = cvtpk_bf16(st[n][14], st[n][15]);
        asm("v_permlane32_swap_b32 %0, %1" : "+v"(T0), "+v"(T2));
        asm("v_permlane32_swap_b32 %0, %1" : "+v"(T1), "+v"(T3));
        asm("v_permlane32_swap_b32 %0, %1" : "+v"(T4), "+v"(T6));
        asm("v_permlane32_swap_b32 %0, %1" : "+v"(T5), "+v"(T7));
        uint4v w0; w0[0] = T0; w0[1] = T1; w0[2] = T2; w0[3] = T3;
        uint4v w1; w1[0] = T4; w1[1] = T5; w1[2] = T6; w1[3] = T7;
        pa[2 * n]     = __builtin_bit_cast(bf16x8, w0);
        pa[2 * n + 1] = __builtin_bit_cast(bf16x8, w1);
      }

      // O^T += V^T P
#pragma unroll
      for (int kk = 0; kk < 4; ++kk) if (kk < 2 * nv)
#pragma unroll
        for (int db = 0; db < 2; ++db)
          acc[db] = __builtin_amdgcn_mfma_f32_32x32x16_bf16(vf[db][kk], pa[kk], acc[db], 0, 0, 0);
    }

    __builtin_amdgcn_s_barrier();  // all waves done reading buf[cur]
    cur ^= 1;
  }

  // epilogue: O[qrow][d] = O^T[d][qrow]/l ; 8B packed stores
  const float lt = l_r + __shfl_xor(l_r, 32);
  const float inv = 1.f / lt;
  const size_t rowbase = (size_t)(b * S + q0w + c) * H + h * 64;
#pragma unroll
  for (int db = 0; db < 2; ++db)
#pragma unroll
    for (int blk = 0; blk < 4; ++blk) {
      ushort4v o;
#pragma unroll
      for (int j = 0; j < 4; ++j) o[j] = f2bf(acc[db][blk * 4 + j] * inv);
      *(ushort4v*)(O + rowbase + db * 32 + blk * 8 + hh * 4) = o;
    }
}

extern "C" void kernel_launch(void* const* d_in, const int* in_sizes, int n_in,
                              void* d_out, int out_size, void* d_ws, size_t ws_size,
                              hipStream_t stream) {
  const float* x     = (const float*)d_in[0];
  const float* w_qkv = (const float*)d_in[1];
  const float* w_out = (const float*)d_in[2];
  const int B = 2, S = 2048, H = 1024;
  const int M = B * S;  // 4096

  // workspace layout (ushort elements), total 48 MB:
  unsigned short* xb    = (unsigned short*)d_ws;        // M*H   (8 MB)  -> reused as VtG
  unsigned short* wqkvT = xb + (size_t)M * H;           // 3H*H  (6 MB)
  unsigned short* woutT = wqkvT + (size_t)3 * H * H;    // H*H   (2 MB)
  unsigned short* qkvb  = woutT + (size_t)H * H;        // M*3H (24 MB)
  unsigned short* Ob    = qkvb + (size_t)M * 3 * H;     // M*H   (8 MB)
  unsigned short* VtG   = xb;  // x-bf16 dead after QKV GEMM; reuse for V^T

  cvt_f32_bf16_kernel<<<1024, 256, 0, stream>>>(x, xb, (M * H) / 4);
  transpose_cvt_kernel<<<dim3((3 * H) / 32, H / 32), 256, 0, stream>>>(w_qkv, wqkvT, H, 3 * H);
  transpose_cvt_kernel<<<dim3(H / 32, H / 32), 256, 0, stream>>>(w_out, woutT, H, H);

  // qkv = x @ w_qkv  (bf16 out, feeds attention)
  gemm_bt_kernel<true><<<dim3(M / 128, (3 * H) / 128), 256, 0, stream>>>(
      xb, wqkvT, qkvb, M, 3 * H, H, H, H, 3 * H);

  // V -> (b,h,d,s) transposed layout (PV A-operand becomes direct LDS-staged loads)
  v_transpose_kernel<<<dim3(S / 32, 32), 256, 0, stream>>>(qkvb, VtG);

  // causal multi-head attention
  attn_kernel<<<dim3(S / 128, 16, B), 256, 0, stream>>>(qkvb, VtG, Ob);

  // out = attn @ w_out (fp32 out)
  gemm_bt_kernel<false><<<dim3(M / 128, H / 128), 256, 0, stream>>>(
      Ob, woutT, d_out, M, H, H, H, H, H);
}

// Round 5
// 138.573 us; speedup vs baseline: 2.1092x; 1.0779x over previous
//
#include <hip/hip_runtime.h>

#define DEVINL __device__ __forceinline__

typedef __attribute__((ext_vector_type(8)))  __bf16         bf16x8;
typedef __attribute__((ext_vector_type(4)))  float          f32x4;
typedef __attribute__((ext_vector_type(16))) float          f32x16;
typedef __attribute__((ext_vector_type(8)))  unsigned short ushort8;
typedef __attribute__((ext_vector_type(4)))  unsigned short ushort4v;
typedef __attribute__((ext_vector_type(4)))  unsigned int   uint4v;
typedef __attribute__((ext_vector_type(4)))  float          float4v;

DEVINL unsigned short f2bf(float f) {
  unsigned int u = __float_as_uint(f);
  u += 0x7fffu + ((u >> 16) & 1u);   // round-to-nearest-even
  return (unsigned short)(u >> 16);
}

DEVINL bf16x8 ldbf8(const unsigned short* p) {
  return __builtin_bit_cast(bf16x8, *(const ushort8*)p);
}

DEVINL unsigned cvtpk_bf16(float lo, float hi) {  // dst.lo16=bf16(lo), dst.hi16=bf16(hi)
  unsigned r;
  asm("v_cvt_pk_bf16_f32 %0, %1, %2" : "=v"(r) : "v"(lo), "v"(hi));
  return r;
}

// async global->LDS, 16B per lane; LDS dest = wave-uniform base + lane*16
DEVINL void gload_lds16(const unsigned short* g, unsigned short* l) {
  __builtin_amdgcn_global_load_lds((const __attribute__((address_space(1))) void*)g,
                                   (__attribute__((address_space(3))) void*)l, 16, 0, 0);
}

// ---------------- fp32 -> bf16 elementwise ----------------
__global__ __launch_bounds__(256) void cvt_f32_bf16_kernel(
    const float* __restrict__ in, unsigned short* __restrict__ out, int n4) {
  int i = blockIdx.x * 256 + threadIdx.x;
  const int stride = gridDim.x * 256;
  for (; i < n4; i += stride) {
    float4v v = *(const float4v*)(in + (size_t)4 * i);
    ushort4v o;
    o[0] = f2bf(v[0]); o[1] = f2bf(v[1]); o[2] = f2bf(v[2]); o[3] = f2bf(v[3]);
    *(ushort4v*)(out + (size_t)4 * i) = o;
  }
}

// ---------------- fp32 (RxC) -> bf16 transposed (CxR) ----------------
__global__ __launch_bounds__(256) void transpose_cvt_kernel(
    const float* __restrict__ in, unsigned short* __restrict__ out, int R, int C) {
  __shared__ float tile[32][33];
  const int tx = threadIdx.x & 31, ty = threadIdx.x >> 5;
  const int r0 = blockIdx.y << 5, c0 = blockIdx.x << 5;
#pragma unroll
  for (int i = 0; i < 32; i += 8)
    tile[ty + i][tx] = in[(size_t)(r0 + ty + i) * C + (c0 + tx)];
  __syncthreads();
#pragma unroll
  for (int i = 0; i < 32; i += 8)
    out[(size_t)(c0 + ty + i) * R + (r0 + tx)] = f2bf(tile[tx][ty + i]);
}

// ---------------- bf16 V transpose: qkv V-third -> Vt[(b,h,d)][s] ----------------
__global__ __launch_bounds__(256) void v_transpose_kernel(
    const unsigned short* __restrict__ qkv, unsigned short* __restrict__ VtG) {
  const int S = 2048, LD = 3072;
  const int s0 = blockIdx.x << 5;
  const int bh = blockIdx.y;           // b*16 + h
  const int b = bh >> 4, h = bh & 15;
  __shared__ __align__(16) unsigned short T[32][72];  // 16B-aligned rows
  const int t = threadIdx.x;
  {
    const int s = t >> 3, d0 = (t & 7) << 3;
    *(ushort8*)&T[s][d0] =
        *(const ushort8*)(qkv + ((size_t)(b * S) + s0 + s) * LD + 2048 + h * 64 + d0);
  }
  __syncthreads();
  {
    const int d = t >> 2, sc = (t & 3) << 3;
    ushort8 o;
#pragma unroll
    for (int e = 0; e < 8; ++e) o[e] = T[sc + e][d];
    *(ushort8*)(VtG + ((size_t)bh * 64 + d) * S + s0 + sc) = o;
  }
}

// ---------------- bf16 GEMM: C = A(MxK) * Bt(NxK)^T ----------------
// 128x128 tile, BK=32, 4 waves (2x2), global_load_lds staging (m97 structure).
template <bool OUT_BF16>
__global__ __launch_bounds__(256) void gemm_bt_kernel(
    const unsigned short* __restrict__ A,   // M x K, lda
    const unsigned short* __restrict__ Bt,  // N x K, ldb
    void* __restrict__ Cout,                // M x N, ldc
    int M, int N, int K, int lda, int ldb, int ldc) {
  __shared__ __align__(16) unsigned short As[128 * 32];
  __shared__ __align__(16) unsigned short Bs[128 * 32];
  const int tid = threadIdx.x;
  const int lane = tid & 63, wave = tid >> 6;
  const int wr = wave >> 1, wc = wave & 1;
  const int g = lane >> 4, q = lane & 15;
  const int row0 = blockIdx.x << 7, col0 = blockIdx.y << 7;

  const int srow = tid >> 2, skcol = (tid & 3) << 3;
  const unsigned short* Ap0 = A + (size_t)(row0 + srow) * lda + skcol;
  const unsigned short* Ap1 = Ap0 + (size_t)64 * lda;
  const unsigned short* Bp0 = Bt + (size_t)(col0 + srow) * ldb + skcol;
  const unsigned short* Bp1 = Bp0 + (size_t)64 * ldb;
  unsigned short* Asw = As + wave * 512;  // wave-uniform LDS base (w*1024 B)
  unsigned short* Bsw = Bs + wave * 512;

  f32x4 acc[4][4] = {};

  for (int k0 = 0; k0 < K; k0 += 32) {
    __syncthreads();               // all waves done reading previous tile
    gload_lds16(Ap0, Asw);
    gload_lds16(Ap1, Asw + 2048);
    gload_lds16(Bp0, Bsw);
    gload_lds16(Bp1, Bsw + 2048);
    Ap0 += 32; Ap1 += 32; Bp0 += 32; Bp1 += 32;
    __syncthreads();               // drains vmcnt -> tile visible

    bf16x8 af[4], bfr[4];
#pragma unroll
    for (int mb = 0; mb < 4; ++mb)
      af[mb] = ldbf8(As + (wr * 64 + mb * 16 + q) * 32 + g * 8);
#pragma unroll
    for (int nb = 0; nb < 4; ++nb)
      bfr[nb] = ldbf8(Bs + (wc * 64 + nb * 16 + q) * 32 + g * 8);
#pragma unroll
    for (int mb = 0; mb < 4; ++mb)
#pragma unroll
      for (int nb = 0; nb < 4; ++nb)
        acc[mb][nb] = __builtin_amdgcn_mfma_f32_16x16x32_bf16(af[mb], bfr[nb], acc[mb][nb], 0, 0, 0);
  }

#pragma unroll
  for (int mb = 0; mb < 4; ++mb)
#pragma unroll
    for (int nb = 0; nb < 4; ++nb)
#pragma unroll
      for (int r = 0; r < 4; ++r) {
        const int row = row0 + wr * 64 + mb * 16 + g * 4 + r;  // C/D: row=(l>>4)*4+reg
        const int col = col0 + wc * 64 + nb * 16 + q;          //       col=l&15
        const float v = acc[mb][nb][r];
        if (OUT_BF16) ((unsigned short*)Cout)[(size_t)row * ldc + col] = f2bf(v);
        else          ((float*)Cout)[(size_t)row * ldc + col] = v;
      }
}

// ---------------- causal flash attention (32x32 MFMA, in-register P) ----------------
// Block = 4 waves x 32 q-rows. K/V staged in LDS (dbuf, counted vmcnt, raw barrier,
// XOR swizzle). Swapped QK^T -> S^T; in-register P via cvt_pk + permlane32_swap.
// Defer-max online softmax (zero cross-lane in common path). Linear grid with
// pair-decode so each CU's 2 resident blocks sum to constant work (qc + 15-qc).
__global__ __launch_bounds__(256, 2) void attn_kernel(
    const unsigned short* __restrict__ qkv,  // (B*S) x 3H row-major
    const unsigned short* __restrict__ VtG,  // (B*16*64) x S : V transposed
    unsigned short* __restrict__ O) {        // (B*S) x H row-major
  const int S = 2048, H = 1024, LD = 3072;
  const int wave = threadIdx.x >> 6, lane = threadIdx.x & 63;
  const int c = lane & 31, hh = lane >> 5;

  // balanced pair decode: CU gets blocks L and L+256 -> qc and 15-qc (34 tiles const)
  const int L = blockIdx.x;
  const int member = L >> 8, r0_ = L & 255;
  const int pairid = r0_ & 7, bh = r0_ >> 3;
  const int qc = member ? (15 - pairid) : pairid;
  const int b = bh >> 4, h = bh & 15;
  const int q0w = qc * 128 + wave * 32;        // this wave's 32 q-rows

  const unsigned short* Qb = qkv + (size_t)b * S * LD + h * 64;
  const unsigned short* Kb = Qb + H;
  const unsigned short* Vt = VtG + (size_t)(b * 16 + h) * 64 * S;

  __shared__ __align__(16) unsigned short Ks[2][64 * 64];   // [kv][d], swizzled
  __shared__ __align__(16) unsigned short Vs[2][64 * 64];   // [d][kv], swizzled

  // staging geometry: 4 x gload_lds16 per wave per tile
  const int srow = lane >> 3;                        // 0..7
  const int srcg = ((lane & 7) ^ srow) << 3;         // pre-swizzled granule (shorts)
  const int wrow = wave * 8 + srow;                  // 0..31

  // prologue: stage tile 0 into buffer 0 (issued before Q loads)
  gload_lds16(Kb + (size_t)wrow * LD + srcg,        Ks[0] + wave * 512);
  gload_lds16(Kb + (size_t)(32 + wrow) * LD + srcg, Ks[0] + 2048 + wave * 512);
  gload_lds16(Vt + (size_t)wrow * S + srcg,         Vs[0] + wave * 512);
  gload_lds16(Vt + (size_t)(32 + wrow) * S + srcg,  Vs[0] + 2048 + wave * 512);

  // Q fragments: lane holds Q[q0w+c][kc*16 + hh*8 + 0..7]
  bf16x8 qf[4];
#pragma unroll
  for (int kc = 0; kc < 4; ++kc)
    qf[kc] = ldbf8(Qb + (size_t)(q0w + c) * LD + kc * 16 + hh * 8);

  f32x16 acc[2] = {};            // O^T: row d = db*32+(r&3)+8(r>>2)+4hh, col = q0w+c
  float m_r = -1e30f, l_r = 0.f; // m uniform across hh pair; l per-lane partial
  const float CE = 0.125f * 1.44269504f;  // 1/sqrt(dh) * log2(e)

  const int ntb = qc * 2 + 2;    // KV tiles this block processes
  int cur = 0;
  const int swz = (c & 7) << 3;  // read-side XOR (shorts)

  for (int t = 0; t < ntb; ++t) {
    if (t + 1 < ntb) {           // issue next tile's loads; stay in flight
      const int c1 = (t + 1) << 6;
      unsigned short* KsN = Ks[cur ^ 1];
      unsigned short* VsN = Vs[cur ^ 1];
      gload_lds16(Kb + (size_t)(c1 + wrow) * LD + srcg,      KsN + wave * 512);
      gload_lds16(Kb + (size_t)(c1 + 32 + wrow) * LD + srcg, KsN + 2048 + wave * 512);
      gload_lds16(Vt + (size_t)wrow * S + c1 + srcg,         VsN + wave * 512);
      gload_lds16(Vt + (size_t)(32 + wrow) * S + c1 + srcg,  VsN + 2048 + wave * 512);
      asm volatile("s_waitcnt vmcnt(4)" ::: "memory");   // tile t resident
    } else {
      asm volatile("s_waitcnt vmcnt(0)" ::: "memory");
    }
    __builtin_amdgcn_s_barrier();  // all waves' stage(t) visible

    const int c0 = t << 6;
    const unsigned short* KsC = Ks[cur];
    const unsigned short* VsC = Vs[cur];

    if (c0 <= q0w + 31) {  // wave has unmasked rows in this tile
      int nv = ((q0w + 31 - c0) >> 5) + 1; if (nv > 2) nv = 2;  // valid 32-kv chunks

      // K fragments: A-operand rows kv = n*32+c, k = kc*16+hh*8
      bf16x8 kf[2][4];
#pragma unroll
      for (int n = 0; n < 2; ++n) if (n < nv)
#pragma unroll
        for (int kc = 0; kc < 4; ++kc)
          kf[n][kc] = ldbf8(KsC + (n * 32 + c) * 64 + ((kc * 16 + hh * 8) ^ swz));

      // S^T = K Q^T : st[n] rows kv, cols qrow
      f32x16 st[2] = {};
#pragma unroll
      for (int n = 0; n < 2; ++n) if (n < nv)
#pragma unroll
        for (int kc = 0; kc < 4; ++kc)
          st[n] = __builtin_amdgcn_mfma_f32_32x32x16_bf16(kf[n][kc], qf[kc], st[n], 0, 0, 0);

      // V fragments early (latency hides under softmax): rows d = db*32+c
      bf16x8 vf[2][4];
#pragma unroll
      for (int db = 0; db < 2; ++db)
#pragma unroll
        for (int kk = 0; kk < 4; ++kk) if (kk < 2 * nv)
          vf[db][kk] = ldbf8(VsC + (db * 32 + c) * 64 + ((kk * 16 + hh * 8) ^ swz));

      if (c0 + 63 > q0w) {  // causal mask (diag region only)
#pragma unroll
        for (int n = 0; n < 2; ++n) if (n < nv)
#pragma unroll
          for (int r = 0; r < 16; ++r) {
            const int kv = c0 + n * 32 + (r & 3) + 8 * (r >> 2) + 4 * hh;
            if (kv > q0w + c) st[n][r] = -1e30f;
          }
      }

      // defer-max online softmax (raw-score domain; 64 raw = 11.5 bits of exp2)
      float pmax = -1e30f;
#pragma unroll
      for (int n = 0; n < 2; ++n) if (n < nv)
#pragma unroll
        for (int r = 0; r < 16; ++r) pmax = fmaxf(pmax, st[n][r]);
      if (!__all(pmax <= m_r + 64.f)) {   // rare: update running max, rescale
        pmax = fmaxf(pmax, __shfl_xor(pmax, 32));
        const float mn = fmaxf(m_r, pmax);
        const float sf = __builtin_amdgcn_exp2f((m_r - mn) * CE);
        m_r = mn; l_r *= sf;
#pragma unroll
        for (int db = 0; db < 2; ++db) acc[db] *= sf;
      }
      const float mC = m_r * CE;
#pragma unroll
      for (int n = 0; n < 2; ++n) if (n < nv)
#pragma unroll
        for (int r = 0; r < 16; ++r) {
          const float p = __builtin_amdgcn_exp2f(fmaf(st[n][r], CE, -mC));
          st[n][r] = p;
          l_r += p;
        }

      // P relayout in-register: cvt_pk pairs then permlane32_swap
      bf16x8 pa[4];
#pragma unroll
      for (int n = 0; n < 2; ++n) if (n < nv) {
        unsigned T0 = cvtpk_bf16(st[n][0],  st[n][1]);
        unsigned T1 = cvtpk_bf16(st[n][2],  st[n][3]);
        unsigned T2 = cvtpk_bf16(st[n][4],  st[n][5]);
        unsigned T3 = cvtpk_bf16(st[n][6],  st[n][7]);
        unsigned T4 = cvtpk_bf16(st[n][8],  st[n][9]);
        unsigned T5 = cvtpk_bf16(st[n][10], st[n][11]);
        unsigned T6 = cvtpk_bf16(st[n][12], st[n][13]);
        unsigned T7 = cvtpk_bf16(st[n][14], st[n][15]);
        asm("v_permlane32_swap_b32 %0, %1" : "+v"(T0), "+v"(T2));
        asm("v_permlane32_swap_b32 %0, %1" : "+v"(T1), "+v"(T3));
        asm("v_permlane32_swap_b32 %0, %1" : "+v"(T4), "+v"(T6));
        asm("v_permlane32_swap_b32 %0, %1" : "+v"(T5), "+v"(T7));
        uint4v w0; w0[0] = T0; w0[1] = T1; w0[2] = T2; w0[3] = T3;
        uint4v w1; w1[0] = T4; w1[1] = T5; w1[2] = T6; w1[3] = T7;
        pa[2 * n]     = __builtin_bit_cast(bf16x8, w0);
        pa[2 * n + 1] = __builtin_bit_cast(bf16x8, w1);
      }

      // O^T += V^T P
#pragma unroll
      for (int kk = 0; kk < 4; ++kk) if (kk < 2 * nv)
#pragma unroll
        for (int db = 0; db < 2; ++db)
          acc[db] = __builtin_amdgcn_mfma_f32_32x32x16_bf16(vf[db][kk], pa[kk], acc[db], 0, 0, 0);
    }

    __builtin_amdgcn_s_barrier();  // all waves done reading buf[cur]
    cur ^= 1;
  }

  // epilogue: O[qrow][d] = O^T[d][qrow]/l ; 8B packed stores
  const float lt = l_r + __shfl_xor(l_r, 32);
  const float inv = 1.f / lt;
  const size_t rowbase = (size_t)(b * S + q0w + c) * H + h * 64;
#pragma unroll
  for (int db = 0; db < 2; ++db)
#pragma unroll
    for (int blk = 0; blk < 4; ++blk) {
      ushort4v o;
#pragma unroll
      for (int j = 0; j < 4; ++j) o[j] = f2bf(acc[db][blk * 4 + j] * inv);
      *(ushort4v*)(O + rowbase + db * 32 + blk * 8 + hh * 4) = o;
    }
}

extern "C" void kernel_launch(void* const* d_in, const int* in_sizes, int n_in,
                              void* d_out, int out_size, void* d_ws, size_t ws_size,
                              hipStream_t stream) {
  const float* x     = (const float*)d_in[0];
  const float* w_qkv = (const float*)d_in[1];
  const float* w_out = (const float*)d_in[2];
  const int B = 2, S = 2048, H = 1024;
  const int M = B * S;  // 4096

  // workspace layout (ushort elements), total 48 MB:
  unsigned short* xb    = (unsigned short*)d_ws;        // M*H   (8 MB)  -> reused as VtG
  unsigned short* wqkvT = xb + (size_t)M * H;           // 3H*H  (6 MB)
  unsigned short* woutT = wqkvT + (size_t)3 * H * H;    // H*H   (2 MB)
  unsigned short* qkvb  = woutT + (size_t)H * H;        // M*3H (24 MB)
  unsigned short* Ob    = qkvb + (size_t)M * 3 * H;     // M*H   (8 MB)
  unsigned short* VtG   = xb;  // x-bf16 dead after QKV GEMM; reuse for V^T

  cvt_f32_bf16_kernel<<<1024, 256, 0, stream>>>(x, xb, (M * H) / 4);
  transpose_cvt_kernel<<<dim3((3 * H) / 32, H / 32), 256, 0, stream>>>(w_qkv, wqkvT, H, 3 * H);
  transpose_cvt_kernel<<<dim3(H / 32, H / 32), 256, 0, stream>>>(w_out, woutT, H, H);

  // qkv = x @ w_qkv  (bf16 out, feeds attention)
  gemm_bt_kernel<true><<<dim3(M / 128, (3 * H) / 128), 256, 0, stream>>>(
      xb, wqkvT, qkvb, M, 3 * H, H, H, H, 3 * H);

  // V -> (b,h,d,s) transposed layout (PV A-operand becomes direct LDS-staged loads)
  v_transpose_kernel<<<dim3(S / 32, 32), 256, 0, stream>>>(qkvb, VtG);

  // causal multi-head attention (512 balanced blocks)
  attn_kernel<<<512, 256, 0, stream>>>(qkvb, VtG, Ob);

  // out = attn @ w_out (fp32 out)
  gemm_bt_kernel<false><<<dim3(M / 128, H / 128), 256, 0, stream>>>(
      Ob, woutT, d_out, M, H, H, H, H, H);
}